// Round 4
// baseline (76.336 us; speedup 1.0000x reference)
//
#include <hip/hip_runtime.h>
#include <hip/hip_bf16.h>

// GraphLSTM fused kernel for MI355X — R3: fixed vmcnt-FIFO pipeline order.
//  - f-gate unused by reference -> skip 1/4 of W_ih/b_ih/b_hh reads.
//  - O=1 conv folded into per-edge scalar: out[b,dst] += ew * dot(conv_w, h).
//  - Persistent waves, lane = h. Per iteration issue order is
//      [x loads for edge e] -> sched_barrier -> [W/bias loads for edge e+1]
//      -> [compute edge e]
//    so waiting on x_e never drains W_{e+1} (vmcnt is FIFO): the next edge's
//    6.4 KB HBM burst stays in flight under the whole compute phase.
//  - Scalars (src/dst/ew) s_loaded one iteration ahead.

#define MN 1024
#define BB 8

__device__ __forceinline__ float fsig(float x) {
    return __builtin_amdgcn_rcpf(1.0f + __expf(-x));
}
__device__ __forceinline__ float ftanh(float x) {
    float t = fminf(fmaxf(2.0f * x, -30.0f), 30.0f);   // avoid inf/inf
    float e = __expf(t);
    return (e - 1.0f) * __builtin_amdgcn_rcpf(e + 1.0f);
}
__device__ __forceinline__ float dot8(const float4& a0, const float4& a1,
                                      const float4& b0, const float4& b1) {
    float r;
    r = a0.x * b0.x;
    r = fmaf(a0.y, b0.y, r);
    r = fmaf(a0.z, b0.z, r);
    r = fmaf(a0.w, b0.w, r);
    r = fmaf(a1.x, b1.x, r);
    r = fmaf(a1.y, b1.y, r);
    r = fmaf(a1.z, b1.z, r);
    r = fmaf(a1.w, b1.w, r);
    return r;
}

// Prep: transpose x (B,D,MN) -> xt (MN,B,D) and init out = conv_b.
__global__ void prep_kernel(const float* __restrict__ x,
                            const float* __restrict__ conv_b,
                            float* __restrict__ xt,
                            float* __restrict__ out) {
    int tid = blockIdx.x * 256 + threadIdx.x;   // 65536 threads
    if (tid < MN * BB * 8) {
        int mn = tid >> 6;
        int b  = (tid >> 3) & 7;
        int d  = tid & 7;
        xt[tid] = x[b * (8 * MN) + d * MN + mn];
    }
    if (tid < BB * MN) out[tid] = conv_b[0];
}

struct WRegs {
    float4 wi0, wi1, wg0, wg1, wo0, wo1;   // 24 VGPR
    float  bIi, bIh, bGi, bGh, bOi, bOh;   // 6 VGPR
};

__device__ __forceinline__ void loadW(WRegs& r, int e, int lane,
        const float* __restrict__ W, const float* __restrict__ b_ih,
        const float* __restrict__ b_hh) {
    const float* We = W + (size_t)e * 2048 + lane * 8;
    r.wi0 = *(const float4*)(We);
    r.wi1 = *(const float4*)(We + 4);
    r.wg0 = *(const float4*)(We + 1024);
    r.wg1 = *(const float4*)(We + 1028);
    r.wo0 = *(const float4*)(We + 1536);
    r.wo1 = *(const float4*)(We + 1540);
    const float* bi = b_ih + (size_t)e * 256 + lane;
    const float* bh = b_hh + (size_t)e * 256 + lane;
    r.bIi = bi[0];   r.bIh = bh[0];
    r.bGi = bi[128]; r.bGh = bh[128];
    r.bOi = bi[192]; r.bOh = bh[192];
}

__device__ __forceinline__ void computeEdge(const WRegs& r, const float4* xv,
        int dst, float ew, float cw, float* __restrict__ out, int lane) {
    float bI = r.bIi + r.bIh;
    float bG = r.bGi + r.bGh;
    float bO = r.bOi + r.bOh;
    float s[BB];
#pragma unroll
    for (int b = 0; b < BB; ++b) {
        float4 xlo = xv[b * 2];
        float4 xhi = xv[b * 2 + 1];
        float pi = bI + dot8(r.wi0, r.wi1, xlo, xhi);
        float pg = bG + dot8(r.wg0, r.wg1, xlo, xhi);
        float po = bO + dot8(r.wo0, r.wo1, xlo, xhi);
        float c  = fsig(pi) * ftanh(pg);
        float h  = fsig(po) * ftanh(c);
        s[b] = cw * h;
    }
    // Batch-folding reduction over 64 lanes (Σ_h), 10 shuffles total.
    float u[4];
#pragma unroll
    for (int k = 0; k < 4; ++k) {
        float keep = (lane & 32) ? s[k + 4] : s[k];
        float send = (lane & 32) ? s[k]     : s[k + 4];
        u[k] = keep + __shfl_xor(send, 32, 64);
    }
    float v[2];
#pragma unroll
    for (int k = 0; k < 2; ++k) {
        float keep = (lane & 16) ? u[k + 2] : u[k];
        float send = (lane & 16) ? u[k]     : u[k + 2];
        v[k] = keep + __shfl_xor(send, 16, 64);
    }
    float keep = (lane & 8) ? v[1] : v[0];
    float send = (lane & 8) ? v[0] : v[1];
    float t = keep + __shfl_xor(send, 8, 64);
    t += __shfl_xor(t, 4, 64);
    t += __shfl_xor(t, 2, 64);
    t += __shfl_xor(t, 1, 64);
    if ((lane & 7) == 0) {
        int b = lane >> 3;
        atomicAdd(out + b * MN + dst, ew * t);
    }
}

__global__ __launch_bounds__(256, 3) void edge_kernel(
        const float* __restrict__ xt,      // (MN, B, D)
        const float* __restrict__ edge_w,  // (E)
        const float* __restrict__ W,       // (E, 256, 8)
        const float* __restrict__ b_ih,    // (E, 256)
        const float* __restrict__ b_hh,    // (E, 256)
        const float* __restrict__ conv_w,  // (1, 64)
        const int*   __restrict__ src_idx,
        const int*   __restrict__ dst_idx,
        float* __restrict__ out,           // (B, MN), pre-initialized to conv_b
        int E) {
    int lane = threadIdx.x & 63;
    int nw = gridDim.x * 4;
    int e0 = __builtin_amdgcn_readfirstlane(blockIdx.x * 4 + (threadIdx.x >> 6));
    if (e0 >= E) return;
    float cw = conv_w[lane];

    WRegs A, B;
    // Stage 0: scalars + W for first edge.
    int   srcC = src_idx[e0];
    int   dstC = dst_idx[e0];
    float ewC  = edge_w[e0];
    loadW(A, e0, lane, W, b_ih, b_hh);

    int  en   = e0 + nw;
    bool useA = true;
    while (true) {
        bool hasNext = (en < E);
        // Scalars for the NEXT edge (s_load; latency hidden under compute).
        int srcN = 0, dstN = 0; float ewN = 0.0f;
        if (hasNext) { srcN = src_idx[en]; dstN = dst_idx[en]; ewN = edge_w[en]; }

        // 1) x loads for CURRENT edge — issued BEFORE next-edge W burst so the
        //    wait for x never drains the prefetch (vmcnt FIFO).
        const float* xe = xt + (size_t)srcC * 64;
        float4 xv[16];
#pragma unroll
        for (int i = 0; i < 16; ++i) xv[i] = *(const float4*)(xe + i * 4);
        __builtin_amdgcn_sched_barrier(0);

        // 2) W/bias burst for NEXT edge.
        if (hasNext) {
            if (useA) loadW(B, en, lane, W, b_ih, b_hh);
            else      loadW(A, en, lane, W, b_ih, b_hh);
        }

        // 3) compute CURRENT edge (waits x_cur + W_cur only).
        if (useA) computeEdge(A, xv, dstC, ewC, cw, out, lane);
        else      computeEdge(B, xv, dstC, ewC, cw, out, lane);

        if (!hasNext) break;
        srcC = srcN; dstC = dstN; ewC = ewN;
        useA = !useA;
        en += nw;
    }
}

extern "C" void kernel_launch(void* const* d_in, const int* in_sizes, int n_in,
                              void* d_out, int out_size, void* d_ws, size_t ws_size,
                              hipStream_t stream) {
    const float* x      = (const float*)d_in[0];
    const float* edge_w = (const float*)d_in[1];
    const float* W_ih   = (const float*)d_in[2];
    const float* b_ih   = (const float*)d_in[3];
    const float* b_hh   = (const float*)d_in[4];
    const float* conv_w = (const float*)d_in[5];
    const float* conv_b = (const float*)d_in[6];
    const int* src_idx  = (const int*)d_in[7];
    const int* dst_idx  = (const int*)d_in[8];
    int E = in_sizes[1];

    float* xt  = (float*)d_ws;      // 65536 floats = 256 KB
    float* out = (float*)d_out;     // 8192 floats

    prep_kernel<<<256, 256, 0, stream>>>(x, conv_b, xt, out);

    // Persistent grid: 3 blocks/CU x 256 CUs.
    edge_kernel<<<768, 256, 0, stream>>>(xt, edge_w, W_ih, b_ih, b_hh,
                                         conv_w, src_idx, dst_idx, out, E);
}

// Round 5
// 71.752 us; speedup vs baseline: 1.0639x; 1.0639x over previous
//
#include <hip/hip_runtime.h>
#include <hip/hip_bf16.h>

// GraphLSTM fused kernel for MI355X — R4: x in 1 VGPR + readlane broadcast,
// clean 2-deep pipeline (scalars 2 ahead, W/x 1 ahead), 4 waves/SIMD.
//  - f-gate unused by reference -> skip 1/4 of W_ih/b_ih/b_hh reads.
//  - O=1 conv folded into per-edge scalar: out[b,dst] += ew * dot(conv_w, h).
//  - x per edge is 64 wave-uniform floats: loaded as ONE coalesced per-lane
//    dword (lane l holds x_l), values extracted via v_readlane into SGPRs and
//    consumed as the scalar operand of v_fma (no duplication, no VGPR cost).
//  - Per iteration issue order: [s_load scalars e+2] [W burst e+1] [x e+1]
//    [compute e]. All of compute e's operands arrived during compute e-1:
//    no vmcnt drains, prefetch always in flight.

#define MN 1024
#define BB 8

__device__ __forceinline__ float fsig(float x) {
    return __builtin_amdgcn_rcpf(1.0f + __expf(-x));
}
__device__ __forceinline__ float ftanh(float x) {
    float t = fminf(fmaxf(2.0f * x, -30.0f), 30.0f);   // avoid inf/inf
    float e = __expf(t);
    return (e - 1.0f) * __builtin_amdgcn_rcpf(e + 1.0f);
}
__device__ __forceinline__ float rl(float v, int idx) {
    return __int_as_float(__builtin_amdgcn_readlane(__float_as_int(v), idx));
}

// Prep: transpose x (B,D,MN) -> xt (MN,B,D) and init out = conv_b.
__global__ void prep_kernel(const float* __restrict__ x,
                            const float* __restrict__ conv_b,
                            float* __restrict__ xt,
                            float* __restrict__ out) {
    int tid = blockIdx.x * 256 + threadIdx.x;   // 65536 threads
    if (tid < MN * BB * 8) {
        int mn = tid >> 6;
        int b  = (tid >> 3) & 7;
        int d  = tid & 7;
        xt[tid] = x[b * (8 * MN) + d * MN + mn];
    }
    if (tid < BB * MN) out[tid] = conv_b[0];
}

struct WRegs {
    float4 wi0, wi1, wg0, wg1, wo0, wo1;   // 24 VGPR
    float  bIi, bIh, bGi, bGh, bOi, bOh;   // 6 VGPR
};

__device__ __forceinline__ void loadW(WRegs& r, int e, int lane,
        const float* __restrict__ W, const float* __restrict__ b_ih,
        const float* __restrict__ b_hh) {
    const float* We = W + (size_t)e * 2048 + lane * 8;
    r.wi0 = *(const float4*)(We);
    r.wi1 = *(const float4*)(We + 4);
    r.wg0 = *(const float4*)(We + 1024);
    r.wg1 = *(const float4*)(We + 1028);
    r.wo0 = *(const float4*)(We + 1536);
    r.wo1 = *(const float4*)(We + 1540);
    const float* bi = b_ih + (size_t)e * 256 + lane;
    const float* bh = b_hh + (size_t)e * 256 + lane;
    r.bIi = bi[0];   r.bIh = bh[0];
    r.bGi = bi[128]; r.bGh = bh[128];
    r.bOi = bi[192]; r.bOh = bh[192];
}

__device__ __forceinline__ void computeEdge(const WRegs& r, float xreg,
        int dst, float ew, float cw, float* __restrict__ out, int lane) {
    float bI = r.bIi + r.bIh;
    float bG = r.bGi + r.bGh;
    float bO = r.bOi + r.bOh;
    float s[BB];
#pragma unroll
    for (int b = 0; b < BB; ++b) {
        // x values live across lanes of xreg; extract as SGPRs (free operand).
        float x0 = rl(xreg, b * 8 + 0), x1 = rl(xreg, b * 8 + 1);
        float x2 = rl(xreg, b * 8 + 2), x3 = rl(xreg, b * 8 + 3);
        float x4 = rl(xreg, b * 8 + 4), x5 = rl(xreg, b * 8 + 5);
        float x6 = rl(xreg, b * 8 + 6), x7 = rl(xreg, b * 8 + 7);
        float pi = bI, pg = bG, po = bO;
        pi = fmaf(r.wi0.x, x0, pi); pg = fmaf(r.wg0.x, x0, pg); po = fmaf(r.wo0.x, x0, po);
        pi = fmaf(r.wi0.y, x1, pi); pg = fmaf(r.wg0.y, x1, pg); po = fmaf(r.wo0.y, x1, po);
        pi = fmaf(r.wi0.z, x2, pi); pg = fmaf(r.wg0.z, x2, pg); po = fmaf(r.wo0.z, x2, po);
        pi = fmaf(r.wi0.w, x3, pi); pg = fmaf(r.wg0.w, x3, pg); po = fmaf(r.wo0.w, x3, po);
        pi = fmaf(r.wi1.x, x4, pi); pg = fmaf(r.wg1.x, x4, pg); po = fmaf(r.wo1.x, x4, po);
        pi = fmaf(r.wi1.y, x5, pi); pg = fmaf(r.wg1.y, x5, pg); po = fmaf(r.wo1.y, x5, po);
        pi = fmaf(r.wi1.z, x6, pi); pg = fmaf(r.wg1.z, x6, pg); po = fmaf(r.wo1.z, x6, po);
        pi = fmaf(r.wi1.w, x7, pi); pg = fmaf(r.wg1.w, x7, pg); po = fmaf(r.wo1.w, x7, po);
        float c = fsig(pi) * ftanh(pg);
        float h = fsig(po) * ftanh(c);
        s[b] = cw * h;
    }
    // Batch-folding reduction over 64 lanes (Σ_h), 10 shuffles total.
    float u[4];
#pragma unroll
    for (int k = 0; k < 4; ++k) {
        float keep = (lane & 32) ? s[k + 4] : s[k];
        float send = (lane & 32) ? s[k]     : s[k + 4];
        u[k] = keep + __shfl_xor(send, 32, 64);
    }
    float v[2];
#pragma unroll
    for (int k = 0; k < 2; ++k) {
        float keep = (lane & 16) ? u[k + 2] : u[k];
        float send = (lane & 16) ? u[k]     : u[k + 2];
        v[k] = keep + __shfl_xor(send, 16, 64);
    }
    float keep = (lane & 8) ? v[1] : v[0];
    float send = (lane & 8) ? v[0] : v[1];
    float t = keep + __shfl_xor(send, 8, 64);
    t += __shfl_xor(t, 4, 64);
    t += __shfl_xor(t, 2, 64);
    t += __shfl_xor(t, 1, 64);
    if ((lane & 7) == 0) {
        int b = lane >> 3;
        atomicAdd(out + b * MN + dst, ew * t);
    }
}

__global__ __launch_bounds__(256, 4) void edge_kernel(
        const float* __restrict__ xt,      // (MN, B, D)
        const float* __restrict__ edge_w,  // (E)
        const float* __restrict__ W,       // (E, 256, 8)
        const float* __restrict__ b_ih,    // (E, 256)
        const float* __restrict__ b_hh,    // (E, 256)
        const float* __restrict__ conv_w,  // (1, 64)
        const int*   __restrict__ src_idx,
        const int*   __restrict__ dst_idx,
        float* __restrict__ out,           // (B, MN), pre-initialized to conv_b
        int E) {
    int lane = threadIdx.x & 63;
    int nw = gridDim.x * 4;
    int e0 = __builtin_amdgcn_readfirstlane(blockIdx.x * 4 + (threadIdx.x >> 6));
    if (e0 >= E) return;
    float cw = conv_w[lane];

    int eC = e0, eN = e0 + nw, eN2 = eN + nw;

    // Startup: scalars for C and N; W+x for C.
    int   srcC = src_idx[eC], dstC = dst_idx[eC];
    float ewC  = edge_w[eC];
    int srcN = 0, dstN = 0; float ewN = 0.0f;
    if (eN < E) { srcN = src_idx[eN]; dstN = dst_idx[eN]; ewN = edge_w[eN]; }

    WRegs A, B;
    loadW(A, eC, lane, W, b_ih, b_hh);
    float xA = xt[(size_t)srcC * 64 + lane];
    float xB = 0.0f;
    bool useA = true;

    while (true) {
        bool hasN  = (eN  < E);
        bool hasN2 = (eN2 < E);
        // Scalars for edge N2 (consumed next iteration).
        int srcN2 = 0, dstN2 = 0; float ewN2 = 0.0f;
        if (hasN2) { srcN2 = src_idx[eN2]; dstN2 = dst_idx[eN2]; ewN2 = edge_w[eN2]; }

        // Prefetch W + x for edge N (srcN s_loaded last iteration — no wait).
        if (hasN) {
            if (useA) { loadW(B, eN, lane, W, b_ih, b_hh);
                        xB = xt[(size_t)srcN * 64 + lane]; }
            else      { loadW(A, eN, lane, W, b_ih, b_hh);
                        xA = xt[(size_t)srcN * 64 + lane]; }
        }
        __builtin_amdgcn_sched_barrier(0);

        // Compute edge C — operands arrived during previous compute.
        if (useA) computeEdge(A, xA, dstC, ewC, cw, out, lane);
        else      computeEdge(B, xB, dstC, ewC, cw, out, lane);

        if (!hasN) break;
        srcC = srcN; dstC = dstN; ewC = ewN;
        srcN = srcN2; dstN = dstN2; ewN = ewN2;
        eC = eN; eN = eN2; eN2 += nw;
        useA = !useA;
    }
}

extern "C" void kernel_launch(void* const* d_in, const int* in_sizes, int n_in,
                              void* d_out, int out_size, void* d_ws, size_t ws_size,
                              hipStream_t stream) {
    const float* x      = (const float*)d_in[0];
    const float* edge_w = (const float*)d_in[1];
    const float* W_ih   = (const float*)d_in[2];
    const float* b_ih   = (const float*)d_in[3];
    const float* b_hh   = (const float*)d_in[4];
    const float* conv_w = (const float*)d_in[5];
    const float* conv_b = (const float*)d_in[6];
    const int* src_idx  = (const int*)d_in[7];
    const int* dst_idx  = (const int*)d_in[8];
    int E = in_sizes[1];

    float* xt  = (float*)d_ws;      // 65536 floats = 256 KB
    float* out = (float*)d_out;     // 8192 floats

    prep_kernel<<<256, 256, 0, stream>>>(x, conv_b, xt, out);

    // Persistent grid: 4 blocks/CU x 256 CUs = 16 waves/CU.
    edge_kernel<<<1024, 256, 0, stream>>>(xt, edge_w, W_ih, b_ih, b_hh,
                                          conv_w, src_idx, dst_idx, out, E);
}